// Round 21
// baseline (225.104 us; speedup 1.0000x reference)
//
#include <hip/hip_runtime.h>
#include <hip/hip_bf16.h>
#include <hip/hip_fp8.h>

#define MROWS 8192   // N*T
#define KDIM  512    // CIN
#define NCOL  8192   // codebook size K
#define TSEQ  2048

typedef float f32x4 __attribute__((ext_vector_type(4)));
typedef long  lx2  __attribute__((ext_vector_type(2)));

__device__ __forceinline__ unsigned int pack4_fp8(float a, float b, float c, float d) {
#if __has_builtin(__builtin_amdgcn_cvt_pk_fp8_f32)
  int r = __builtin_amdgcn_cvt_pk_fp8_f32(a, b, 0, false);
  r = __builtin_amdgcn_cvt_pk_fp8_f32(c, d, r, true);
  return (unsigned int)r;
#else
  __hip_fp8_e4m3 ha(a), hb(b), hc(c), hd(d);
  return (unsigned int)ha.__x | ((unsigned int)hb.__x << 8) |
         ((unsigned int)hc.__x << 16) | ((unsigned int)hd.__x << 24);
#endif
}

// exact OCP e4m3 decode
__device__ __forceinline__ float fp8d(unsigned char b) {
  unsigned int s = b >> 7, e = (b >> 3) & 15, m = b & 7;
  if (e == 0) {
    float v = (float)m * 0.001953125f;
    return s ? -v : v;
  }
  unsigned int bits = (s << 31) | ((e + 120) << 23) | (m << 20);
  return __uint_as_float(bits);
}

// Fragment-packed layout v2 (wave-contiguous): row-group g = r>>4, quad q = g>>2,
// sub s = g&3, K-tile t. chunk id = (q*8 + t)*4 + s. 1KB chunk = 64 lanes x 16B;
// lane slot = l16*16 + (r&15); lane 16B: low 8B = k [t*64+l16*8..+8), high = +32.
__device__ __forceinline__ size_t pk_addr(int r, int kb) {
  int t = kb >> 6, tb = kb & 63;
  int ks = tb >> 5, rem = tb & 31;
  int l16 = rem >> 3, bo = rem & 7;
  int g = r >> 4;
  size_t chunk = (size_t)(((g >> 2) * 8 + t) * 4 + (g & 3));
  return (chunk << 10) + (((l16 << 4) + (r & 15)) << 4) + (ks << 3) + bo;
}

// ================= shared device pieces =================
__device__ __forceinline__ void convA_chunk(const float* __restrict__ X,
                                            unsigned char* __restrict__ A8,
                                            int n, int lane) {
  const int l15 = lane & 15, l16 = (lane >> 4) & 3;
  const int s = n & 3, t = (n >> 2) & 7, q = n >> 5;
  const int r = (q * 4 + s) * 16 + l15;
  const float* base = X + (size_t)r * KDIM + t * 64 + l16 * 8;
  const float4* s0 = reinterpret_cast<const float4*>(base);
  const float4* s1 = reinterpret_cast<const float4*>(base + 32);
  float4 a0 = s0[0], a1 = s0[1], b0 = s1[0], b1 = s1[1];
  uint4 o;
  o.x = pack4_fp8(a0.x, a0.y, a0.z, a0.w);
  o.y = pack4_fp8(a1.x, a1.y, a1.z, a1.w);
  o.z = pack4_fp8(b0.x, b0.y, b0.z, b0.w);
  o.w = pack4_fp8(b1.x, b1.y, b1.z, b1.w);
  *reinterpret_cast<uint4*>(A8 + (size_t)n * 1024 + lane * 16) = o;
}

__device__ __forceinline__ void convB_tile(const float* __restrict__ W,
                                           unsigned char* __restrict__ B8,
                                           float (*tile)[65], int tb, int tid) {
  const int wave = tid >> 6, lane = tid & 63;
  const int l15 = lane & 15, l16 = (lane >> 4) & 3;
  const int bx = tb & 127, by = tb >> 7;
  const int c4 = tid & 15, rr = tid >> 4;
  #pragma unroll
  for (int p = 0; p < 4; ++p) {
    int row = p * 16 + rr;
    float4 v = reinterpret_cast<const float4*>(W + (size_t)(by * 64 + row) * NCOL + bx * 64)[c4];
    tile[row][c4 * 4 + 0] = v.x; tile[row][c4 * 4 + 1] = v.y;
    tile[row][c4 * 4 + 2] = v.z; tile[row][c4 * 4 + 3] = v.w;
  }
  __syncthreads();
  const int G = bx * 4 + wave;
  const int oc = wave * 16 + l15;
  const int kl = l16 * 8;
  float f0[8], f1[8];
  #pragma unroll
  for (int j = 0; j < 8; ++j) { f0[j] = tile[kl + j][oc]; f1[j] = tile[32 + kl + j][oc]; }
  uint4 o;
  o.x = pack4_fp8(f0[0], f0[1], f0[2], f0[3]);
  o.y = pack4_fp8(f0[4], f0[5], f0[6], f0[7]);
  o.z = pack4_fp8(f1[0], f1[1], f1[2], f1[3]);
  o.w = pack4_fp8(f1[4], f1[5], f1[6], f1[7]);
  const size_t chunk = (size_t)(((G >> 2) * 8 + by) * 4 + (G & 3));
  *reinterpret_cast<uint4*>(B8 + chunk * 1024 + lane * 16) = o;
}

__device__ __forceinline__ void fproj_rows(const float* __restrict__ feats,
                                           const float* __restrict__ proj,
                                           float* __restrict__ F, int blk, int tid) {
  int rl = tid >> 4, d = tid & 15;
  int row = blk * 16 + rl;
  const float4* fr4 = reinterpret_cast<const float4*>(feats + (size_t)row * KDIM);
  float acc = 0.f;
  #pragma unroll 4
  for (int kc = 0; kc < KDIM / 4; ++kc) {
    float4 v = fr4[kc];
    const float* p = proj + (size_t)kc * 64 + d;
    acc += v.x * p[0] + v.y * p[16] + v.z * p[32] + v.w * p[48];
  }
  F[(size_t)row * 16 + d] = acc;   // unnormalized: argmax dot == ref argmin (unit-norm codes)
}

__device__ __forceinline__ void targets_slice(const float* __restrict__ F,
                                              const float* __restrict__ cb,
                                              unsigned long long* __restrict__ amin,
                                              float (*csh)[16], int sl, int tid) {
  const int r0 = (sl & 7) * 1024 + tid;
  const int c0 = (sl >> 3) * 128;
  {
    int ci = tid >> 1, half = tid & 1;
    const float4* src = reinterpret_cast<const float4*>(cb + (size_t)(c0 + ci) * 16 + half * 8);
    float4 v0 = src[0], v1 = src[1];
    float4* dst = reinterpret_cast<float4*>(&csh[ci][half * 8]);
    dst[0] = v0; dst[1] = v1;
  }
  float4 fa[4][4];
  #pragma unroll
  for (int q = 0; q < 4; ++q) {
    const float4* fp = reinterpret_cast<const float4*>(F + (size_t)(r0 + q * 256) * 16);
    fa[q][0] = fp[0]; fa[q][1] = fp[1]; fa[q][2] = fp[2]; fa[q][3] = fp[3];
  }
  __syncthreads();
  float best[4] = {3.4e38f, 3.4e38f, 3.4e38f, 3.4e38f};
  int bidx[4] = {0, 0, 0, 0};
  #pragma unroll 2
  for (int ci = 0; ci < 128; ++ci) {
    const float4* cvp = reinterpret_cast<const float4*>(&csh[ci][0]);
    float4 c0v = cvp[0], c1v = cvp[1], c2v = cvp[2], c3v = cvp[3];
    #pragma unroll
    for (int q = 0; q < 4; ++q) {
      float dot = fa[q][0].x*c0v.x + fa[q][0].y*c0v.y + fa[q][0].z*c0v.z + fa[q][0].w*c0v.w
                + fa[q][1].x*c1v.x + fa[q][1].y*c1v.y + fa[q][1].z*c1v.z + fa[q][1].w*c1v.w
                + fa[q][2].x*c2v.x + fa[q][2].y*c2v.y + fa[q][2].z*c2v.z + fa[q][2].w*c2v.w
                + fa[q][3].x*c3v.x + fa[q][3].y*c3v.y + fa[q][3].z*c3v.z + fa[q][3].w*c3v.w;
      float d = -dot;
      if (d < best[q]) { best[q] = d; bidx[q] = c0 + ci; }
    }
  }
  #pragma unroll
  for (int q = 0; q < 4; ++q) {
    unsigned int u = __float_as_uint(best[q]);
    unsigned int key = (u & 0x80000000u) ? ~u : (u | 0x80000000u);  // order-preserving
    unsigned long long pk = ((unsigned long long)key << 32) | (unsigned int)bidx[q];
    atomicMin(&amin[r0 + q * 256], pk);
  }
}

__device__ __forceinline__ void gemm_tile(const unsigned char* __restrict__ A,
                                          const unsigned char* __restrict__ B,
                                          const float* __restrict__ bias,
                                          float* __restrict__ rowsum,
                                          int gid, int tid) {
  const int wave = tid >> 6, lane = tid & 63;
  const int xcd = gid & 7, idx = gid >> 3;
  const int bx = xcd * 8 + (idx & 7);
  const int by = idx >> 3;
  const int row0 = by * 128, col0 = bx * 128;
  const int wr = wave >> 1, wc = wave & 1;

  f32x4 acc[4][4];
  #pragma unroll
  for (int i = 0; i < 4; ++i)
    #pragma unroll
    for (int j = 0; j < 4; ++j) acc[i][j] = (f32x4){0.f, 0.f, 0.f, 0.f};

  const unsigned char* abase = A + ((size_t)(by * 2 + wr) << 15) + lane * 16;
  const unsigned char* bbase = B + ((size_t)(bx * 2 + wc) << 15) + lane * 16;

  #pragma unroll
  for (int t = 0; t < 8; ++t) {
    lx2 afr[4], bfr[4];
    #pragma unroll
    for (int mi = 0; mi < 4; ++mi)
      afr[mi] = *reinterpret_cast<const lx2*>(abase + t * 4096 + mi * 1024);
    #pragma unroll
    for (int ni = 0; ni < 4; ++ni)
      bfr[ni] = *reinterpret_cast<const lx2*>(bbase + t * 4096 + ni * 1024);
    #pragma unroll
    for (int mi = 0; mi < 4; ++mi)
      #pragma unroll
      for (int ni = 0; ni < 4; ++ni) {
        acc[mi][ni] = __builtin_amdgcn_mfma_f32_16x16x32_fp8_fp8(afr[mi][0], bfr[ni][0], acc[mi][ni], 0, 0, 0);
        acc[mi][ni] = __builtin_amdgcn_mfma_f32_16x16x32_fp8_fp8(afr[mi][1], bfr[ni][1], acc[mi][ni], 0, 0, 0);
      }
  }

  const int l15 = lane & 15, l16 = lane >> 4;
  float bv[4];
  #pragma unroll
  for (int ni = 0; ni < 4; ++ni)
    bv[ni] = bias[col0 + wc * 64 + ni * 16 + l15];
  #pragma unroll
  for (int mi = 0; mi < 4; ++mi) {
    int rbase = row0 + wr * 64 + mi * 16 + l16 * 4;
    #pragma unroll
    for (int j = 0; j < 4; ++j) {
      float se = 0.f;
      #pragma unroll
      for (int ni = 0; ni < 4; ++ni)
        se += __expf(acc[mi][ni][j] + bv[ni]);
      #pragma unroll
      for (int o = 1; o < 16; o <<= 1) se += __shfl_xor(se, o);
      if (l15 == 0) atomicAdd(&rowsum[rbase + j], se);
    }
  }
}

__device__ __forceinline__ void tgtloss_row(const unsigned char* __restrict__ A,
                                            const unsigned char* __restrict__ B,
                                            const float* __restrict__ bias,
                                            const unsigned long long* __restrict__ amin,
                                            const float* __restrict__ rowsum,
                                            const int* __restrict__ lens,
                                            float* __restrict__ out,
                                            int r, int lane, float inv) {
  const int tg = (int)(amin[r] & 0xffffffffull);
  const int kb = lane << 3;
  uint2 ua = *reinterpret_cast<const uint2*>(A + pk_addr(r, kb));
  uint2 ub = *reinterpret_cast<const uint2*>(B + pk_addr(tg, kb));
  float s = 0.f;
  const unsigned char* pa = reinterpret_cast<const unsigned char*>(&ua);
  const unsigned char* pb = reinterpret_cast<const unsigned char*>(&ub);
  #pragma unroll
  for (int k = 0; k < 8; ++k) s += fp8d(pa[k]) * fp8d(pb[k]);
  #pragma unroll
  for (int o = 1; o < 64; o <<= 1) s += __shfl_xor(s, o);
  if (lane == 0) {
    const int n = r >> 11, t = r & (TSEQ - 1);
    if (t < lens[n]) atomicAdd(out, (logf(rowsum[r]) - (s + bias[tg])) * inv);
  }
}

// ================= 3-kernel pipeline (proven best: R17/R19 lineage) =================
__global__ void prep_kernel(const float* __restrict__ X, unsigned char* __restrict__ A8,
                            const float* __restrict__ W, unsigned char* __restrict__ B8,
                            const float* __restrict__ feats, const float* __restrict__ proj,
                            float* __restrict__ F, unsigned long long* __restrict__ amin,
                            float* __restrict__ rowsum, float* __restrict__ out) {
  __shared__ float tile[64][65];
  const int tid = threadIdx.x;
  const int wave = tid >> 6, lane = tid & 63;
  int b = blockIdx.x;
  if (b < 1024) {
    convA_chunk(X, A8, b * 4 + wave, lane);
  } else if (b < 2048) {
    convB_tile(W, B8, tile, b - 1024, tid);
  } else if (b < 2560) {
    fproj_rows(feats, proj, F, b - 2048, tid);
  } else {
    int r = (b - 2560) * 256 + tid;
    amin[r] = ~0ull;
    rowsum[r] = 0.f;
    if (b == 2560 && tid == 0) out[0] = 0.f;
  }
}

#define TGT_BLOCKS 512
__global__ __launch_bounds__(256, 4)
void gemm_targets_kernel(const unsigned char* __restrict__ A,
                         const unsigned char* __restrict__ B,
                         const float* __restrict__ bias,
                         float* __restrict__ rowsum,
                         const float* __restrict__ F,
                         const float* __restrict__ cb,
                         unsigned long long* __restrict__ amin) {
  __shared__ __align__(16) float csh[128][16];
  const int tid = threadIdx.x;
  const int bid = blockIdx.x;
  if (bid < TGT_BLOCKS) {
    targets_slice(F, cb, amin, csh, bid, tid);
    return;
  }
  gemm_tile(A, B, bias, rowsum, bid - TGT_BLOCKS, tid);
}

__global__ void tgtloss_kernel(const unsigned char* __restrict__ A,
                               const unsigned char* __restrict__ B,
                               const float* __restrict__ bias,
                               const unsigned long long* __restrict__ amin,
                               const float* __restrict__ rowsum,
                               const int* __restrict__ lens,
                               float* __restrict__ out) {
  const int wave = threadIdx.x >> 6, lane = threadIdx.x & 63;
  const int cnt = lens[0] + lens[1] + lens[2] + lens[3];
  const float inv = 1.0f / (float)max(cnt, 1);
  tgtloss_row(A, B, bias, amin, rowsum, lens, out, blockIdx.x * 4 + wave, lane, inv);
}

extern "C" void kernel_launch(void* const* d_in, const int* in_sizes, int n_in,
                              void* d_out, int out_size, void* d_ws, size_t ws_size,
                              hipStream_t stream) {
  const float* feats    = (const float*)d_in[0];
  const float* context  = (const float*)d_in[1];
  const int*   lens     = (const int*)d_in[2];
  const float* proj     = (const float*)d_in[3];
  const float* codebook = (const float*)d_in[4];
  const float* W_enc    = (const float*)d_in[5];
  const float* b_enc    = (const float*)d_in[6];
  float* out = (float*)d_out;

  char* ws = (char*)d_ws;
  unsigned char* A8 = (unsigned char*)(ws);                       // 4 MB (packed v2)
  unsigned char* B8 = (unsigned char*)(ws + 4194304);             // 4 MB (packed v2)
  float* F          = (float*)(ws + 8388608);                     // 512 KB
  unsigned long long* amin = (unsigned long long*)(ws + 8912896); // 64 KB
  float* rowsum     = (float*)(ws + 8978432);                     // 32 KB

  // 1) conversions (fragment-packed v2, coalesced chunk writes) + projection + init
  prep_kernel<<<2592, 256, 0, stream>>>(context, A8, W_enc, B8, feats, proj, F, amin, rowsum, out);
  // 2) codebook argmax (first 512 blocks)  ||  barrier-free reg-direct GEMM + rowsum(exp)
  gemm_targets_kernel<<<TGT_BLOCKS + 4096, 256, 0, stream>>>(A8, B8, b_enc, rowsum, F, codebook, amin);
  // 3) target logit + masked-mean loss
  tgtloss_kernel<<<2048, 256, 0, stream>>>(A8, B8, b_enc, amin, rowsum, lens, out);
}

// Round 22
// 167.320 us; speedup vs baseline: 1.3454x; 1.3454x over previous
//
#include <hip/hip_runtime.h>
#include <hip/hip_bf16.h>
#include <hip/hip_fp8.h>

#define MROWS 8192   // N*T
#define KDIM  512    // CIN
#define NCOL  8192   // codebook size K
#define TSEQ  2048

typedef float f32x4 __attribute__((ext_vector_type(4)));
typedef long  lx2  __attribute__((ext_vector_type(2)));

__device__ __forceinline__ unsigned int pack4_fp8(float a, float b, float c, float d) {
#if __has_builtin(__builtin_amdgcn_cvt_pk_fp8_f32)
  int r = __builtin_amdgcn_cvt_pk_fp8_f32(a, b, 0, false);
  r = __builtin_amdgcn_cvt_pk_fp8_f32(c, d, r, true);
  return (unsigned int)r;
#else
  __hip_fp8_e4m3 ha(a), hb(b), hc(c), hd(d);
  return (unsigned int)ha.__x | ((unsigned int)hb.__x << 8) |
         ((unsigned int)hc.__x << 16) | ((unsigned int)hd.__x << 24);
#endif
}

// exact OCP e4m3 decode
__device__ __forceinline__ float fp8d(unsigned char b) {
  unsigned int s = b >> 7, e = (b >> 3) & 15, m = b & 7;
  if (e == 0) {
    float v = (float)m * 0.001953125f;
    return s ? -v : v;
  }
  unsigned int bits = (s << 31) | ((e + 120) << 23) | (m << 20);
  return __uint_as_float(bits);
}

// Fragment-packed layout v2 (wave-contiguous): row-group g = r>>4, quad q = g>>2,
// sub s = g&3, K-tile t. chunk id = (q*8 + t)*4 + s. 1KB chunk = 64 lanes x 16B;
// lane slot = l16*16 + (r&15); lane 16B: low 8B = k [t*64+l16*8..+8), high = +32.
__device__ __forceinline__ size_t pk_addr(int r, int kb) {
  int t = kb >> 6, tb = kb & 63;
  int ks = tb >> 5, rem = tb & 31;
  int l16 = rem >> 3, bo = rem & 7;
  int g = r >> 4;
  size_t chunk = (size_t)(((g >> 2) * 8 + t) * 4 + (g & 3));
  return (chunk << 10) + (((l16 << 4) + (r & 15)) << 4) + (ks << 3) + bo;
}

// ================= shared device pieces =================
__device__ __forceinline__ void convA_chunk(const float* __restrict__ X,
                                            unsigned char* __restrict__ A8,
                                            int n, int lane) {
  const int l15 = lane & 15, l16 = (lane >> 4) & 3;
  const int s = n & 3, t = (n >> 2) & 7, q = n >> 5;
  const int r = (q * 4 + s) * 16 + l15;
  const float* base = X + (size_t)r * KDIM + t * 64 + l16 * 8;
  const float4* s0 = reinterpret_cast<const float4*>(base);
  const float4* s1 = reinterpret_cast<const float4*>(base + 32);
  float4 a0 = s0[0], a1 = s0[1], b0 = s1[0], b1 = s1[1];
  uint4 o;
  o.x = pack4_fp8(a0.x, a0.y, a0.z, a0.w);
  o.y = pack4_fp8(a1.x, a1.y, a1.z, a1.w);
  o.z = pack4_fp8(b0.x, b0.y, b0.z, b0.w);
  o.w = pack4_fp8(b1.x, b1.y, b1.z, b1.w);
  *reinterpret_cast<uint4*>(A8 + (size_t)n * 1024 + lane * 16) = o;
}

__device__ __forceinline__ void convB_tile(const float* __restrict__ W,
                                           unsigned char* __restrict__ B8,
                                           float (*tile)[65], int tb, int tid) {
  const int wave = tid >> 6, lane = tid & 63;
  const int l15 = lane & 15, l16 = (lane >> 4) & 3;
  const int bx = tb & 127, by = tb >> 7;
  const int c4 = tid & 15, rr = tid >> 4;
  #pragma unroll
  for (int p = 0; p < 4; ++p) {
    int row = p * 16 + rr;
    float4 v = reinterpret_cast<const float4*>(W + (size_t)(by * 64 + row) * NCOL + bx * 64)[c4];
    tile[row][c4 * 4 + 0] = v.x; tile[row][c4 * 4 + 1] = v.y;
    tile[row][c4 * 4 + 2] = v.z; tile[row][c4 * 4 + 3] = v.w;
  }
  __syncthreads();
  const int G = bx * 4 + wave;
  const int oc = wave * 16 + l15;
  const int kl = l16 * 8;
  float f0[8], f1[8];
  #pragma unroll
  for (int j = 0; j < 8; ++j) { f0[j] = tile[kl + j][oc]; f1[j] = tile[32 + kl + j][oc]; }
  uint4 o;
  o.x = pack4_fp8(f0[0], f0[1], f0[2], f0[3]);
  o.y = pack4_fp8(f0[4], f0[5], f0[6], f0[7]);
  o.z = pack4_fp8(f1[0], f1[1], f1[2], f1[3]);
  o.w = pack4_fp8(f1[4], f1[5], f1[6], f1[7]);
  const size_t chunk = (size_t)(((G >> 2) * 8 + by) * 4 + (G & 3));
  *reinterpret_cast<uint4*>(B8 + chunk * 1024 + lane * 16) = o;
}

__device__ __forceinline__ void fproj_rows(const float* __restrict__ feats,
                                           const float* __restrict__ proj,
                                           float* __restrict__ F, int blk, int tid) {
  int rl = tid >> 4, d = tid & 15;
  int row = blk * 16 + rl;
  const float4* fr4 = reinterpret_cast<const float4*>(feats + (size_t)row * KDIM);
  float acc = 0.f;
  #pragma unroll 4
  for (int kc = 0; kc < KDIM / 4; ++kc) {
    float4 v = fr4[kc];
    const float* p = proj + (size_t)kc * 64 + d;
    acc += v.x * p[0] + v.y * p[16] + v.z * p[32] + v.w * p[48];
  }
  F[(size_t)row * 16 + d] = acc;   // unnormalized: argmax dot == ref argmin (unit-norm codes)
}

__device__ __forceinline__ void targets_slice(const float* __restrict__ F,
                                              const float* __restrict__ cb,
                                              unsigned long long* __restrict__ amin,
                                              float (*csh)[16], int sl, int tid) {
  const int r0 = (sl & 7) * 1024 + tid;
  const int c0 = (sl >> 3) * 128;
  {
    int ci = tid >> 1, half = tid & 1;
    const float4* src = reinterpret_cast<const float4*>(cb + (size_t)(c0 + ci) * 16 + half * 8);
    float4 v0 = src[0], v1 = src[1];
    float4* dst = reinterpret_cast<float4*>(&csh[ci][half * 8]);
    dst[0] = v0; dst[1] = v1;
  }
  float4 fa[4][4];
  #pragma unroll
  for (int q = 0; q < 4; ++q) {
    const float4* fp = reinterpret_cast<const float4*>(F + (size_t)(r0 + q * 256) * 16);
    fa[q][0] = fp[0]; fa[q][1] = fp[1]; fa[q][2] = fp[2]; fa[q][3] = fp[3];
  }
  __syncthreads();
  float best[4] = {3.4e38f, 3.4e38f, 3.4e38f, 3.4e38f};
  int bidx[4] = {0, 0, 0, 0};
  #pragma unroll 2
  for (int ci = 0; ci < 128; ++ci) {
    const float4* cvp = reinterpret_cast<const float4*>(&csh[ci][0]);
    float4 c0v = cvp[0], c1v = cvp[1], c2v = cvp[2], c3v = cvp[3];
    #pragma unroll
    for (int q = 0; q < 4; ++q) {
      float dot = fa[q][0].x*c0v.x + fa[q][0].y*c0v.y + fa[q][0].z*c0v.z + fa[q][0].w*c0v.w
                + fa[q][1].x*c1v.x + fa[q][1].y*c1v.y + fa[q][1].z*c1v.z + fa[q][1].w*c1v.w
                + fa[q][2].x*c2v.x + fa[q][2].y*c2v.y + fa[q][2].z*c2v.z + fa[q][2].w*c2v.w
                + fa[q][3].x*c3v.x + fa[q][3].y*c3v.y + fa[q][3].z*c3v.z + fa[q][3].w*c3v.w;
      float d = -dot;
      if (d < best[q]) { best[q] = d; bidx[q] = c0 + ci; }
    }
  }
  #pragma unroll
  for (int q = 0; q < 4; ++q) {
    unsigned int u = __float_as_uint(best[q]);
    unsigned int key = (u & 0x80000000u) ? ~u : (u | 0x80000000u);  // order-preserving
    unsigned long long pk = ((unsigned long long)key << 32) | (unsigned int)bidx[q];
    atomicMin(&amin[r0 + q * 256], pk);
  }
}

__device__ __forceinline__ void gemm_tile(const unsigned char* __restrict__ A,
                                          const unsigned char* __restrict__ B,
                                          const float* __restrict__ bias,
                                          float* __restrict__ rowsum,
                                          int gid, int tid) {
  const int wave = tid >> 6, lane = tid & 63;
  const int xcd = gid & 7, idx = gid >> 3;
  const int bx = xcd * 8 + (idx & 7);
  const int by = idx >> 3;
  const int row0 = by * 128, col0 = bx * 128;
  const int wr = wave >> 1, wc = wave & 1;

  f32x4 acc[4][4];
  #pragma unroll
  for (int i = 0; i < 4; ++i)
    #pragma unroll
    for (int j = 0; j < 4; ++j) acc[i][j] = (f32x4){0.f, 0.f, 0.f, 0.f};

  const unsigned char* abase = A + ((size_t)(by * 2 + wr) << 15) + lane * 16;
  const unsigned char* bbase = B + ((size_t)(bx * 2 + wc) << 15) + lane * 16;

  #pragma unroll
  for (int t = 0; t < 8; ++t) {
    lx2 afr[4], bfr[4];
    #pragma unroll
    for (int mi = 0; mi < 4; ++mi)
      afr[mi] = *reinterpret_cast<const lx2*>(abase + t * 4096 + mi * 1024);
    #pragma unroll
    for (int ni = 0; ni < 4; ++ni)
      bfr[ni] = *reinterpret_cast<const lx2*>(bbase + t * 4096 + ni * 1024);
    #pragma unroll
    for (int mi = 0; mi < 4; ++mi)
      #pragma unroll
      for (int ni = 0; ni < 4; ++ni) {
        acc[mi][ni] = __builtin_amdgcn_mfma_f32_16x16x32_fp8_fp8(afr[mi][0], bfr[ni][0], acc[mi][ni], 0, 0, 0);
        acc[mi][ni] = __builtin_amdgcn_mfma_f32_16x16x32_fp8_fp8(afr[mi][1], bfr[ni][1], acc[mi][ni], 0, 0, 0);
      }
  }

  const int l15 = lane & 15, l16 = lane >> 4;
  float bv[4];
  #pragma unroll
  for (int ni = 0; ni < 4; ++ni)
    bv[ni] = bias[col0 + wc * 64 + ni * 16 + l15];
  #pragma unroll
  for (int mi = 0; mi < 4; ++mi) {
    int rbase = row0 + wr * 64 + mi * 16 + l16 * 4;
    #pragma unroll
    for (int j = 0; j < 4; ++j) {
      float se = 0.f;
      #pragma unroll
      for (int ni = 0; ni < 4; ++ni)
        se += __expf(acc[mi][ni][j] + bv[ni]);
      #pragma unroll
      for (int o = 1; o < 16; o <<= 1) se += __shfl_xor(se, o);
      if (l15 == 0) atomicAdd(&rowsum[rbase + j], se);
    }
  }
}

// ================= 3-kernel pipeline (proven best: R17/R19 lineage) =================
__global__ void prep_kernel(const float* __restrict__ X, unsigned char* __restrict__ A8,
                            const float* __restrict__ W, unsigned char* __restrict__ B8,
                            const float* __restrict__ feats, const float* __restrict__ proj,
                            float* __restrict__ F, unsigned long long* __restrict__ amin,
                            float* __restrict__ rowsum, float* __restrict__ out) {
  __shared__ float tile[64][65];
  const int tid = threadIdx.x;
  const int wave = tid >> 6, lane = tid & 63;
  int b = blockIdx.x;
  if (b < 1024) {
    convA_chunk(X, A8, b * 4 + wave, lane);
  } else if (b < 2048) {
    convB_tile(W, B8, tile, b - 1024, tid);
  } else if (b < 2560) {
    fproj_rows(feats, proj, F, b - 2048, tid);
  } else {
    int r = (b - 2560) * 256 + tid;
    amin[r] = ~0ull;
    rowsum[r] = 0.f;
    if (b == 2560 && tid == 0) out[0] = 0.f;
  }
}

#define TGT_BLOCKS 512
__global__ __launch_bounds__(256, 4)
void gemm_targets_kernel(const unsigned char* __restrict__ A,
                         const unsigned char* __restrict__ B,
                         const float* __restrict__ bias,
                         float* __restrict__ rowsum,
                         const float* __restrict__ F,
                         const float* __restrict__ cb,
                         unsigned long long* __restrict__ amin) {
  __shared__ __align__(16) float csh[128][16];
  const int tid = threadIdx.x;
  const int bid = blockIdx.x;
  if (bid < TGT_BLOCKS) {
    targets_slice(F, cb, amin, csh, bid, tid);
    return;
  }
  gemm_tile(A, B, bias, rowsum, bid - TGT_BLOCKS, tid);
}

// tgt logit + masked-mean loss: block = 4 rows; LDS reduce -> ONE atomicAdd per block
__global__ void tgtloss_kernel(const unsigned char* __restrict__ A,
                               const unsigned char* __restrict__ B,
                               const float* __restrict__ bias,
                               const unsigned long long* __restrict__ amin,
                               const float* __restrict__ rowsum,
                               const int* __restrict__ lens,
                               float* __restrict__ out) {
  __shared__ float sp[4];
  const int wave = threadIdx.x >> 6, lane = threadIdx.x & 63;
  const int cnt = lens[0] + lens[1] + lens[2] + lens[3];
  const float inv = 1.0f / (float)max(cnt, 1);
  const int r = blockIdx.x * 4 + wave;
  const int tg = (int)(amin[r] & 0xffffffffull);
  const int kb = lane << 3;
  uint2 ua = *reinterpret_cast<const uint2*>(A + pk_addr(r, kb));
  uint2 ub = *reinterpret_cast<const uint2*>(B + pk_addr(tg, kb));
  float s = 0.f;
  const unsigned char* pa = reinterpret_cast<const unsigned char*>(&ua);
  const unsigned char* pb = reinterpret_cast<const unsigned char*>(&ub);
  #pragma unroll
  for (int k = 0; k < 8; ++k) s += fp8d(pa[k]) * fp8d(pb[k]);
  #pragma unroll
  for (int o = 1; o < 64; o <<= 1) s += __shfl_xor(s, o);
  if (lane == 0) {
    const int n = r >> 11, t = r & (TSEQ - 1);
    sp[wave] = (t < lens[n]) ? (logf(rowsum[r]) - (s + bias[tg])) * inv : 0.f;
  }
  __syncthreads();
  if (threadIdx.x == 0)
    atomicAdd(out, sp[0] + sp[1] + sp[2] + sp[3]);
}

extern "C" void kernel_launch(void* const* d_in, const int* in_sizes, int n_in,
                              void* d_out, int out_size, void* d_ws, size_t ws_size,
                              hipStream_t stream) {
  const float* feats    = (const float*)d_in[0];
  const float* context  = (const float*)d_in[1];
  const int*   lens     = (const int*)d_in[2];
  const float* proj     = (const float*)d_in[3];
  const float* codebook = (const float*)d_in[4];
  const float* W_enc    = (const float*)d_in[5];
  const float* b_enc    = (const float*)d_in[6];
  float* out = (float*)d_out;

  char* ws = (char*)d_ws;
  unsigned char* A8 = (unsigned char*)(ws);                       // 4 MB (packed v2)
  unsigned char* B8 = (unsigned char*)(ws + 4194304);             // 4 MB (packed v2)
  float* F          = (float*)(ws + 8388608);                     // 512 KB
  unsigned long long* amin = (unsigned long long*)(ws + 8912896); // 64 KB
  float* rowsum     = (float*)(ws + 8978432);                     // 32 KB

  // 1) conversions (fragment-packed v2, coalesced chunk writes) + projection + init
  prep_kernel<<<2592, 256, 0, stream>>>(context, A8, W_enc, B8, feats, proj, F, amin, rowsum, out);
  // 2) codebook argmax (first 512 blocks)  ||  barrier-free reg-direct GEMM + rowsum(exp)
  gemm_targets_kernel<<<TGT_BLOCKS + 4096, 256, 0, stream>>>(A8, B8, b_enc, rowsum, F, codebook, amin);
  // 3) target logit + masked-mean loss
  tgtloss_kernel<<<2048, 256, 0, stream>>>(A8, B8, b_enc, amin, rowsum, lens, out);
}